// Round 1
// baseline (252.903 us; speedup 1.0000x reference)
//
#include <hip/hip_runtime.h>
#include <math.h>

// Problem constants (match reference)
constexpr int NB = 32, NM = 64, NK = 8400, NC = 80, NT = 15;
constexpr float FEPS = 1e-7f;

// Output layout: [tso | tgt_bboxes | assign | overlaps | fg], all float32
constexpr size_t OUT_TSO = 0;
constexpr size_t OUT_TGT = (size_t)NB * NK * NC;            // 21504000
constexpr size_t OUT_ASN = OUT_TGT + (size_t)NB * NK * 4;   // 22579200
constexpr size_t OUT_OVL = OUT_ASN + (size_t)NB * NM * NK;  // 39782400
constexpr size_t OUT_FG  = OUT_OVL + (size_t)NB * NM * NK;  // 56985600

// ---------------------------------------------------------------------------
// Kernel A: one block per (b,m) gt row.
//   - computes overlaps row (written to d_out) and align-metric row (LDS)
//   - row max of overlaps -> ovmax[bm]
//   - top-15 of am (value desc, index asc tie-break) -> tki/tkv lists
//   - pre-filter per-(b,k) membership counts -> fg0 atomics; flag = any>=2
// ---------------------------------------------------------------------------
__global__ __launch_bounds__(256) void kA(
    const float* __restrict__ points, const float* __restrict__ gt_bboxes,
    const int* __restrict__ gt_labels, const float* __restrict__ pred_bboxes,
    const float* __restrict__ pred_scores, const int* __restrict__ gt_mask,
    float* __restrict__ out, int* __restrict__ tki, float* __restrict__ tkv,
    float* __restrict__ ovmaxp, int* __restrict__ fg0, int* __restrict__ flag)
{
  __shared__ float amrow[NK];    // 33.6 KB
  __shared__ float redv[256];
  __shared__ int   redi[256];
  __shared__ int   s_done;

  const int bm = blockIdx.x;
  const int b  = bm >> 6;
  const int t  = threadIdx.x;

  const int   maskv = gt_mask[bm];
  const float4 g = *(const float4*)(gt_bboxes + (size_t)bm * 4);
  const int   label = gt_labels[bm];

  float* ovl_out = out + OUT_OVL + (size_t)bm * NK;
  const float4* pb  = (const float4*)(pred_bboxes + (size_t)b * NK * 4);
  const float2* pts = (const float2*)points;
  const float*  ps  = pred_scores + (size_t)b * NK * NC;

  const float w1 = g.z - g.x, h1 = g.w - g.y;
  const float at1 = atanf(w1 / (h1 + FEPS));
  const float area1 = w1 * h1;
  const float CV = (float)(4.0 / (M_PI * M_PI));        // rounded once, like numpy
  const float ONE_EPS = (float)(1.0 + 1e-7);            // 1.0 + EPS in f64, then f32

  float lmax = 0.f;
  for (int k = t; k < NK; k += 256) {
    float ov = 0.f, am = 0.f;
    if (maskv) {
      float2 p = pts[k];
      // diff.max(-1) < 1e-6 : all four single-subtraction comparisons (exact f32)
      float dmax = fmaxf(fmaxf(g.x - p.x, g.y - p.y), fmaxf(p.x - g.z, p.y - g.w));
      if (dmax < 1e-6f) {
        float4 q = pb[k];
        float w2 = q.z - q.x, h2 = q.w - q.y;
        float iw = fmaxf(fminf(g.z, q.z) - fmaxf(g.x, q.x), 0.f);
        float ih = fmaxf(fminf(g.w, q.w) - fmaxf(g.y, q.y), 0.f);
        float inter = iw * ih;
        float uni = area1 + w2 * h2 - inter + FEPS;
        float iou = inter / uni;
        float cw = fmaxf(g.z, q.z) - fminf(g.x, q.x);
        float ch = fmaxf(g.w, q.w) - fminf(g.y, q.y);
        float c2 = cw * cw + ch * ch + FEPS;
        float ex = q.x + q.z - g.x - g.z;
        float ey = q.y + q.w - g.y - g.w;
        float rho2 = (ex * ex + ey * ey) * 0.25f;
        float dat = atanf(w2 / (h2 + FEPS)) - at1;
        float v = CV * dat * dat;
        float alpha = v / (v - iou + ONE_EPS);
        float ciou = iou - (rho2 / c2 + alpha * v);
        ov = fmaxf(ciou, 0.f);
        float ts = ps[(size_t)k * NC + label];
        float o2 = ov * ov;
        am = ts * (o2 * o2 * o2);   // ts**1 * ov**6
      }
    }
    ovl_out[k] = ov;
    amrow[k] = am;
    lmax = fmaxf(lmax, ov);
  }

  // row max of overlaps
  redv[t] = lmax;
  __syncthreads();
  for (int s = 128; s > 0; s >>= 1) {
    if (t < s) redv[t] = fmaxf(redv[t], redv[t + s]);
    __syncthreads();
  }
  if (t == 0) { ovmaxp[bm] = redv[0]; s_done = 0; }
  __syncthreads();

  // top-15 by iterative argmax (value desc, lowest index on ties)
  for (int it = 0; it < NT; ++it) {
    float bv = -1.f; int bi = NK;
    if (!s_done) {
      for (int k = t; k < NK; k += 256) {
        float v = amrow[k];
        if (v > bv) { bv = v; bi = k; }   // strided ascending -> lowest idx kept
      }
    }
    redv[t] = bv; redi[t] = bi;
    __syncthreads();
    for (int s = 128; s > 0; s >>= 1) {
      if (t < s) {
        float v2 = redv[t + s]; int i2 = redi[t + s];
        if (v2 > redv[t] || (v2 == redv[t] && i2 < redi[t])) { redv[t] = v2; redi[t] = i2; }
      }
      __syncthreads();
    }
    if (t == 0) {
      float v = redv[0]; int idx = redi[0];
      if (!s_done && v > 1e-9f) {          // tkm = tkv > 1e-9
        tki[bm * NT + it] = idx;
        tkv[bm * NT + it] = v;
        amrow[idx] = -1.f;                 // exclude from later iterations
        int old = atomicAdd(&fg0[(size_t)b * NK + idx], 1);
        if (old >= 1) atomicOr(flag, 1);   // some pred assigned to >=2 gts
      } else {
        s_done = 1;
        tki[bm * NT + it] = -1;
        tkv[bm * NT + it] = 0.f;
      }
    }
    __syncthreads();
  }
}

// ---------------------------------------------------------------------------
// Kernel Mi: per (b,k), argmax over m of overlaps (first max wins)
// ---------------------------------------------------------------------------
__global__ __launch_bounds__(256) void kMi(const float* __restrict__ out,
                                           int* __restrict__ mi)
{
  const int b = blockIdx.y;
  const int k = blockIdx.x * 256 + threadIdx.x;
  if (k >= NK) return;
  const float* ovl = out + OUT_OVL + (size_t)b * NM * NK;
  float best = ovl[k]; int bi = 0;
  for (int m = 1; m < NM; ++m) {
    float v = ovl[(size_t)m * NK + k];
    if (v > best) { best = v; bi = m; }    // strict > keeps first max (jnp.argmax)
  }
  mi[(size_t)b * NK + k] = bi;
}

// ---------------------------------------------------------------------------
// Kernel D: per (b,k) column. Membership via LDS scatter of top-15 lists.
// Writes assign, fg, tgt_bboxes; stores label & fg*factor for kernel E.
// ---------------------------------------------------------------------------
constexpr int DH = 32;  // process m in two halves to keep LDS at ~41.5 KB

__global__ __launch_bounds__(256) void kD(
    const float* __restrict__ gt_bboxes, const int* __restrict__ gt_labels,
    const int* __restrict__ tki, const float* __restrict__ tkv,
    const float* __restrict__ ovmaxp, const int* __restrict__ mi,
    const int* __restrict__ flagp, float* __restrict__ out,
    int* __restrict__ labelw, float* __restrict__ tsoval)
{
  __shared__ float  vals[DH][256];     // 32 KB: am value if (m,k) in top15 else 0
  __shared__ int    s_tki[NM * NT];    // 3.84 KB
  __shared__ float  s_tkv[NM * NT];    // 3.84 KB
  __shared__ float  s_rowmax[NM];
  __shared__ float  s_ovmax[NM];
  __shared__ int    s_label[NM];
  __shared__ float4 s_gtb[NM];

  const int b  = blockIdx.y;
  const int k0 = blockIdx.x * 256;
  const int t  = threadIdx.x;
  const int flag = *flagp;

  for (int e = t; e < NM * NT; e += 256) {
    s_tki[e] = tki[b * NM * NT + e];
    s_tkv[e] = tkv[b * NM * NT + e];
  }
  if (t < NM) {
    s_ovmax[t] = ovmaxp[b * NM + t];
    s_label[t] = gt_labels[b * NM + t];
    s_gtb[t] = *(const float4*)(gt_bboxes + (size_t)(b * NM + t) * 4);
  }
  __syncthreads();

  // post-filter row max of am_a (am * assign): over surviving top-15 entries
  if (t < NM) {
    float r = 0.f;
    for (int j = 0; j < NT; ++j) {
      int idx = s_tki[t * NT + j];
      if (idx >= 0 && (!flag || mi[(size_t)b * NK + idx] == t))
        r = fmaxf(r, s_tkv[t * NT + j]);
    }
    s_rowmax[t] = r;
  }

  const int k = k0 + t;
  const int mik = (k < NK) ? mi[(size_t)b * NK + k] : 0;
  int cnt = 0, tbi = -1;
  float factor = 0.f;

  for (int half = 0; half < 2; ++half) {
    __syncthreads();
    for (int e = t; e < DH * 256; e += 256) ((float*)vals)[e] = 0.f;
    __syncthreads();
    const int mbase = half * DH;
    for (int e = t; e < DH * NT; e += 256) {
      int mm = mbase + e / NT;
      int idx = s_tki[mm * NT + (e % NT)];
      if (idx >= k0 && idx < k0 + 256) vals[e / NT][idx - k0] = s_tkv[mm * NT + (e % NT)];
    }
    __syncthreads();
    if (k < NK) {
      for (int mo = 0; mo < DH; ++mo) {
        const int m = mbase + mo;
        float v = vals[mo][t];
        bool keep = (v > 1e-9f) && (!flag || mik == m);
        out[OUT_ASN + (size_t)(b * NM + m) * NK + k] = keep ? 1.f : 0.f;
        if (keep) {
          if (cnt == 0) tbi = m;
          cnt++;
          factor = fmaxf(factor, v / (s_rowmax[m] + 1e-9f) * s_ovmax[m]);
        }
      }
    }
  }

  if (k < NK) {
    const int tb = (tbi < 0) ? 0 : tbi;   // argmax of all-zero column -> 0
    out[OUT_FG + (size_t)b * NK + k] = (float)cnt;
    *(float4*)(out + OUT_TGT + (size_t)(b * NK + k) * 4) = s_gtb[tb];
    labelw[b * NK + k] = s_label[tb];
    tsoval[b * NK + k] = (cnt > 0) ? factor : 0.f;
  }
}

// ---------------------------------------------------------------------------
// Kernel E: tso[b,k,c] = (c == label) * fg * factor   (86 MB coalesced write)
// ---------------------------------------------------------------------------
__global__ __launch_bounds__(256) void kE(const int* __restrict__ labelw,
                                          const float* __restrict__ tsoval,
                                          float* __restrict__ out)
{
  const int i = blockIdx.x * 256 + threadIdx.x;
  if (i >= NB * NK * NC) return;
  const int bk = i / NC;
  const int c  = i - bk * NC;
  float v = (c == labelw[bk]) ? tsoval[bk] : 0.f;
  out[OUT_TSO + (size_t)i] = v;
}

// ---------------------------------------------------------------------------
extern "C" void kernel_launch(void* const* d_in, const int* in_sizes, int n_in,
                              void* d_out, int out_size, void* d_ws, size_t ws_size,
                              hipStream_t stream)
{
  const float* points      = (const float*)d_in[0];
  const float* gt_bboxes   = (const float*)d_in[1];
  const int*   gt_labels   = (const int*)d_in[2];
  const float* pred_bboxes = (const float*)d_in[3];
  const float* pred_scores = (const float*)d_in[4];
  const int*   gt_mask     = (const int*)d_in[5];
  float* out = (float*)d_out;

  char* ws = (char*)d_ws;
  int*   tki    = (int*)ws;    ws += (size_t)NB * NM * NT * 4;   // 122880
  float* tkv    = (float*)ws;  ws += (size_t)NB * NM * NT * 4;   // 122880
  float* ovmaxp = (float*)ws;  ws += (size_t)NB * NM * 4;        // 8192
  int*   mi     = (int*)ws;    ws += (size_t)NB * NK * 4;        // 1075200
  int*   labelw = (int*)ws;    ws += (size_t)NB * NK * 4;
  float* tsoval = (float*)ws;  ws += (size_t)NB * NK * 4;
  int*   fg0    = (int*)ws;    ws += (size_t)NB * NK * 4;
  int*   flag   = (int*)ws;    // 4 bytes (+pad)

  // fg0 + flag must be zero at the start of every call (ws is poisoned once)
  hipMemsetAsync(fg0, 0, (size_t)NB * NK * 4 + 16, stream);

  kA<<<NB * NM, 256, 0, stream>>>(points, gt_bboxes, gt_labels, pred_bboxes,
                                  pred_scores, gt_mask, out, tki, tkv, ovmaxp,
                                  fg0, flag);

  dim3 g2((NK + 255) / 256, NB);
  kMi<<<g2, 256, 0, stream>>>(out, mi);
  kD<<<g2, 256, 0, stream>>>(gt_bboxes, gt_labels, tki, tkv, ovmaxp, mi, flag,
                             out, labelw, tsoval);

  const int nE = NB * NK * NC;
  kE<<<(nE + 255) / 256, 256, 0, stream>>>(labelw, tsoval, out);
}

// Round 2
// 208.061 us; speedup vs baseline: 1.2155x; 1.2155x over previous
//
#include <hip/hip_runtime.h>
#include <math.h>

// Problem constants (match reference)
constexpr int NB = 32, NM = 64, NK = 8400, NC = 80, NT = 15;
constexpr int NJ = 33;                 // ceil(NK/256)
constexpr float FEPS = 1e-7f;

// Output layout: [tso | tgt_bboxes | assign | overlaps | fg], all float32
constexpr size_t OUT_TSO = 0;
constexpr size_t OUT_TGT = (size_t)NB * NK * NC;            // 21504000
constexpr size_t OUT_ASN = OUT_TGT + (size_t)NB * NK * 4;   // 22579200
constexpr size_t OUT_OVL = OUT_ASN + (size_t)NB * NM * NK;  // 39782400
constexpr size_t OUT_FG  = OUT_OVL + (size_t)NB * NM * NK;  // 56985600

// ---------------------------------------------------------------------------
// Kernel A: one block per (b,m) gt row.
//   - per-thread am values stay in REGISTERS (av[33])
//   - top-15 via iterative argmax: shfl butterfly + 4-wide LDS combine,
//     only the winning thread rescans its registers. 1 barrier/round.
//   - writes overlaps row, ovmax, top-15 lists, fg0 atomics + conflict flag
// ---------------------------------------------------------------------------
__global__ __launch_bounds__(256) void kA(
    const float* __restrict__ points, const float* __restrict__ gt_bboxes,
    const int* __restrict__ gt_labels, const float* __restrict__ pred_bboxes,
    const float* __restrict__ pred_scores, const int* __restrict__ gt_mask,
    float* __restrict__ out, int* __restrict__ tki, float* __restrict__ tkv,
    float* __restrict__ ovmaxp, int* __restrict__ fg0, int* __restrict__ flag)
{
  __shared__ float s_m[4];
  __shared__ float s_rv[2][4];
  __shared__ int   s_ri[2][4];

  const int bm = blockIdx.x;
  const int b  = bm >> 6;
  const int t  = threadIdx.x;
  const int wid = t >> 6, lane = t & 63;

  const int   maskv = gt_mask[bm];
  const float4 g = *(const float4*)(gt_bboxes + (size_t)bm * 4);
  const int   label = gt_labels[bm];

  float* ovl_out = out + OUT_OVL + (size_t)bm * NK;
  const float4* pb  = (const float4*)(pred_bboxes + (size_t)b * NK * 4);
  const float2* pts = (const float2*)points;
  const float*  ps  = pred_scores + (size_t)b * NK * NC;

  const float w1 = g.z - g.x, h1 = g.w - g.y;
  const float at1 = atanf(w1 / (h1 + FEPS));
  const float area1 = w1 * h1;
  const float CV = (float)(4.0 / (M_PI * M_PI));
  const float ONE_EPS = (float)(1.0 + 1e-7);

  float av[NJ];          // per-thread am values, -1 = invalid/consumed
  float lmax = 0.f;

  #pragma unroll
  for (int j = 0; j < NJ; ++j) {
    const int k = t + j * 256;
    float ov = 0.f, am = -1.f;
    if (k < NK) {
      am = 0.f;
      if (maskv) {
        float2 p = pts[k];
        // diff.max(-1) < 1e-6 : all four single-subtraction comparisons
        float dmax = fmaxf(fmaxf(g.x - p.x, g.y - p.y), fmaxf(p.x - g.z, p.y - g.w));
        if (dmax < 1e-6f) {
          float4 q = pb[k];
          float w2 = q.z - q.x, h2 = q.w - q.y;
          float iw = fmaxf(fminf(g.z, q.z) - fmaxf(g.x, q.x), 0.f);
          float ih = fmaxf(fminf(g.w, q.w) - fmaxf(g.y, q.y), 0.f);
          float inter = iw * ih;
          float uni = area1 + w2 * h2 - inter + FEPS;
          float iou = inter / uni;
          float cw = fmaxf(g.z, q.z) - fminf(g.x, q.x);
          float ch = fmaxf(g.w, q.w) - fminf(g.y, q.y);
          float c2 = cw * cw + ch * ch + FEPS;
          float ex = q.x + q.z - g.x - g.z;
          float ey = q.y + q.w - g.y - g.w;
          float rho2 = (ex * ex + ey * ey) * 0.25f;
          float dat = atanf(w2 / (h2 + FEPS)) - at1;
          float v = CV * dat * dat;
          float alpha = v / (v - iou + ONE_EPS);
          float ciou = iou - (rho2 / c2 + alpha * v);
          ov = fmaxf(ciou, 0.f);
          float ts = ps[(size_t)k * NC + label];
          float o2 = ov * ov;
          am = ts * (o2 * o2 * o2);   // ts**1 * ov**6
        }
      }
      ovl_out[k] = ov;
    }
    av[j] = am;
    lmax = fmaxf(lmax, ov);
  }

  // row max of overlaps: wave butterfly + 4-wide LDS combine
  {
    float mv = lmax;
    #pragma unroll
    for (int d = 1; d < 64; d <<= 1) mv = fmaxf(mv, __shfl_xor(mv, d));
    if (lane == 0) s_m[wid] = mv;
  }
  __syncthreads();
  if (t == 0)
    ovmaxp[bm] = fmaxf(fmaxf(s_m[0], s_m[1]), fmaxf(s_m[2], s_m[3]));

  // per-thread running best (value desc, lowest index on tie)
  float bv = -2.f; int bi = NK;
  #pragma unroll
  for (int j = 0; j < NJ; ++j)
    if (av[j] > bv) { bv = av[j]; bi = t + j * 256; }   // ascending j -> lowest idx

  int it = 0;
  for (; it < NT; ++it) {
    // wave butterfly on (value, index)
    float wv = bv; int wi = bi;
    #pragma unroll
    for (int d = 1; d < 64; d <<= 1) {
      float ov2 = __shfl_xor(wv, d);
      int   oi2 = __shfl_xor(wi, d);
      if (ov2 > wv || (ov2 == wv && oi2 < wi)) { wv = ov2; wi = oi2; }
    }
    if (lane == 0) { s_rv[it & 1][wid] = wv; s_ri[it & 1][wid] = wi; }
    __syncthreads();
    float fv = s_rv[it & 1][0]; int fi = s_ri[it & 1][0];
    #pragma unroll
    for (int w = 1; w < 4; ++w) {
      float v2 = s_rv[it & 1][w]; int i2 = s_ri[it & 1][w];
      if (v2 > fv || (v2 == fv && i2 < fi)) { fv = v2; fi = i2; }
    }
    if (fv <= 1e-9f) break;          // uniform across block

    if (t == 0) {
      tki[bm * NT + it] = fi;
      tkv[bm * NT + it] = fv;
      int old = atomicAdd(&fg0[(size_t)b * NK + fi], 1);
      if (old >= 1) atomicOr(flag, 1);
    }
    // winner thread consumes its value and rescans registers
    if (((fi - t) & 255) == 0) {
      const int slot = (fi - t) >> 8;
      #pragma unroll
      for (int j = 0; j < NJ; ++j) if (j == slot) av[j] = -1.f;
      bv = -2.f; bi = NK;
      #pragma unroll
      for (int j = 0; j < NJ; ++j)
        if (av[j] > bv) { bv = av[j]; bi = t + j * 256; }
    }
  }
  if (t == 0)
    for (int r = it; r < NT; ++r) { tki[bm * NT + r] = -1; tkv[bm * NT + r] = 0.f; }
}

// ---------------------------------------------------------------------------
// Kernel Mi: per (b,k), argmax over m of overlaps (first max wins)
// ---------------------------------------------------------------------------
__global__ __launch_bounds__(256) void kMi(const float* __restrict__ out,
                                           int* __restrict__ mi)
{
  const int b = blockIdx.y;
  const int k = blockIdx.x * 256 + threadIdx.x;
  if (k >= NK) return;
  const float* ovl = out + OUT_OVL + (size_t)b * NM * NK;
  float best = ovl[k]; int bi = 0;
  for (int m = 1; m < NM; ++m) {
    float v = ovl[(size_t)m * NK + k];
    if (v > best) { best = v; bi = m; }    // strict > keeps first max (jnp.argmax)
  }
  mi[(size_t)b * NK + k] = bi;
}

// ---------------------------------------------------------------------------
// Kernel D: per (b,k) column. Membership via LDS scatter of top-15 lists.
// Writes assign, fg, tgt_bboxes; stores label & fg*factor for kernel E.
// ---------------------------------------------------------------------------
constexpr int DH = 32;  // process m in two halves to keep LDS at ~41.5 KB

__global__ __launch_bounds__(256) void kD(
    const float* __restrict__ gt_bboxes, const int* __restrict__ gt_labels,
    const int* __restrict__ tki, const float* __restrict__ tkv,
    const float* __restrict__ ovmaxp, const int* __restrict__ mi,
    const int* __restrict__ flagp, float* __restrict__ out,
    int* __restrict__ labelw, float* __restrict__ tsoval)
{
  __shared__ float  vals[DH][256];     // 32 KB: am value if (m,k) in top15 else 0
  __shared__ int    s_tki[NM * NT];    // 3.84 KB
  __shared__ float  s_tkv[NM * NT];    // 3.84 KB
  __shared__ float  s_rowmax[NM];
  __shared__ float  s_ovmax[NM];
  __shared__ int    s_label[NM];
  __shared__ float4 s_gtb[NM];

  const int b  = blockIdx.y;
  const int k0 = blockIdx.x * 256;
  const int t  = threadIdx.x;
  const int flag = *flagp;

  for (int e = t; e < NM * NT; e += 256) {
    s_tki[e] = tki[b * NM * NT + e];
    s_tkv[e] = tkv[b * NM * NT + e];
  }
  if (t < NM) {
    s_ovmax[t] = ovmaxp[b * NM + t];
    s_label[t] = gt_labels[b * NM + t];
    s_gtb[t] = *(const float4*)(gt_bboxes + (size_t)(b * NM + t) * 4);
  }
  __syncthreads();

  // post-filter row max of am_a (am * assign): over surviving top-15 entries
  if (t < NM) {
    float r = 0.f;
    for (int j = 0; j < NT; ++j) {
      int idx = s_tki[t * NT + j];
      if (idx >= 0 && (!flag || mi[(size_t)b * NK + idx] == t))
        r = fmaxf(r, s_tkv[t * NT + j]);
    }
    s_rowmax[t] = r;
  }

  const int k = k0 + t;
  const int mik = (k < NK) ? mi[(size_t)b * NK + k] : 0;
  int cnt = 0, tbi = -1;
  float factor = 0.f;

  for (int half = 0; half < 2; ++half) {
    __syncthreads();
    for (int e = t; e < DH * 256; e += 256) ((float*)vals)[e] = 0.f;
    __syncthreads();
    const int mbase = half * DH;
    for (int e = t; e < DH * NT; e += 256) {
      int mm = mbase + e / NT;
      int idx = s_tki[mm * NT + (e % NT)];
      if (idx >= k0 && idx < k0 + 256) vals[e / NT][idx - k0] = s_tkv[mm * NT + (e % NT)];
    }
    __syncthreads();
    if (k < NK) {
      for (int mo = 0; mo < DH; ++mo) {
        const int m = mbase + mo;
        float v = vals[mo][t];
        bool keep = (v > 1e-9f) && (!flag || mik == m);
        out[OUT_ASN + (size_t)(b * NM + m) * NK + k] = keep ? 1.f : 0.f;
        if (keep) {
          if (cnt == 0) tbi = m;
          cnt++;
          factor = fmaxf(factor, v / (s_rowmax[m] + 1e-9f) * s_ovmax[m]);
        }
      }
    }
  }

  if (k < NK) {
    const int tb = (tbi < 0) ? 0 : tbi;   // argmax of all-zero column -> 0
    out[OUT_FG + (size_t)b * NK + k] = (float)cnt;
    *(float4*)(out + OUT_TGT + (size_t)(b * NK + k) * 4) = s_gtb[tb];
    labelw[b * NK + k] = s_label[tb];
    tsoval[b * NK + k] = (cnt > 0) ? factor : 0.f;
  }
}

// ---------------------------------------------------------------------------
// Kernel E: tso[b,k,c] = (c == label) * fg * factor   (86 MB coalesced write)
// ---------------------------------------------------------------------------
__global__ __launch_bounds__(256) void kE(const int* __restrict__ labelw,
                                          const float* __restrict__ tsoval,
                                          float* __restrict__ out)
{
  const int i = blockIdx.x * 256 + threadIdx.x;
  if (i >= NB * NK * NC) return;
  const int bk = i / NC;
  const int c  = i - bk * NC;
  float v = (c == labelw[bk]) ? tsoval[bk] : 0.f;
  out[OUT_TSO + (size_t)i] = v;
}

// ---------------------------------------------------------------------------
extern "C" void kernel_launch(void* const* d_in, const int* in_sizes, int n_in,
                              void* d_out, int out_size, void* d_ws, size_t ws_size,
                              hipStream_t stream)
{
  const float* points      = (const float*)d_in[0];
  const float* gt_bboxes   = (const float*)d_in[1];
  const int*   gt_labels   = (const int*)d_in[2];
  const float* pred_bboxes = (const float*)d_in[3];
  const float* pred_scores = (const float*)d_in[4];
  const int*   gt_mask     = (const int*)d_in[5];
  float* out = (float*)d_out;

  char* ws = (char*)d_ws;
  int*   tki    = (int*)ws;    ws += (size_t)NB * NM * NT * 4;   // 122880
  float* tkv    = (float*)ws;  ws += (size_t)NB * NM * NT * 4;   // 122880
  float* ovmaxp = (float*)ws;  ws += (size_t)NB * NM * 4;        // 8192
  int*   mi     = (int*)ws;    ws += (size_t)NB * NK * 4;        // 1075200
  int*   labelw = (int*)ws;    ws += (size_t)NB * NK * 4;
  float* tsoval = (float*)ws;  ws += (size_t)NB * NK * 4;
  int*   fg0    = (int*)ws;    ws += (size_t)NB * NK * 4;
  int*   flag   = (int*)ws;    // 4 bytes (+pad)

  // fg0 + flag must be zero at the start of every call (ws is poisoned once)
  hipMemsetAsync(fg0, 0, (size_t)NB * NK * 4 + 16, stream);

  kA<<<NB * NM, 256, 0, stream>>>(points, gt_bboxes, gt_labels, pred_bboxes,
                                  pred_scores, gt_mask, out, tki, tkv, ovmaxp,
                                  fg0, flag);

  dim3 g2((NK + 255) / 256, NB);
  kMi<<<g2, 256, 0, stream>>>(out, mi);
  kD<<<g2, 256, 0, stream>>>(gt_bboxes, gt_labels, tki, tkv, ovmaxp, mi, flag,
                             out, labelw, tsoval);

  const int nE = NB * NK * NC;
  kE<<<(nE + 255) / 256, 256, 0, stream>>>(labelw, tsoval, out);
}

// Round 3
// 153.459 us; speedup vs baseline: 1.6480x; 1.3558x over previous
//
#include <hip/hip_runtime.h>
#include <math.h>

// Problem constants (match reference)
constexpr int NB = 32, NM = 64, NK = 8400, NC = 80, NT = 15;
constexpr int NQ = 4, KQ = 2100;       // k split into 4 quarters of 2100
constexpr float FEPS = 1e-7f;

// Output layout: [tso | tgt_bboxes | assign | overlaps | fg], all float32
constexpr size_t OUT_TSO = 0;
constexpr size_t OUT_TGT = (size_t)NB * NK * NC;            // 21504000
constexpr size_t OUT_ASN = OUT_TGT + (size_t)NB * NK * 4;   // 22579200
constexpr size_t OUT_OVL = OUT_ASN + (size_t)NB * NM * NK;  // 39782400
constexpr size_t OUT_FG  = OUT_OVL + (size_t)NB * NM * NK;  // 56985600

// ---------------------------------------------------------------------------
// kP: patan[b,k] = atanf(w2/(h2+eps)) — hoists atanf out of the (m) loop
// ---------------------------------------------------------------------------
__global__ __launch_bounds__(256) void kP(const float* __restrict__ pred_bboxes,
                                          float* __restrict__ patan)
{
  const int i = blockIdx.x * 256 + threadIdx.x;
  if (i >= NB * NK) return;
  float4 q = ((const float4*)pred_bboxes)[i];
  patan[i] = atanf((q.z - q.x) / ((q.w - q.y) + FEPS));
}

// ---------------------------------------------------------------------------
// kA1: one block per (b,m,quarter). Computes overlaps for its k-range,
// collects positives (am>1e-9) into LDS, wave-0 extracts per-quarter top-15
// via packed-key (value desc, index asc) butterfly argmax.
// ---------------------------------------------------------------------------
__global__ __launch_bounds__(256) void kA1(
    const float* __restrict__ points, const float* __restrict__ gt_bboxes,
    const int* __restrict__ gt_labels, const float* __restrict__ pred_bboxes,
    const float* __restrict__ pred_scores, const int* __restrict__ gt_mask,
    const float* __restrict__ patan, float* __restrict__ out,
    float* __restrict__ candv, int* __restrict__ candi,
    float* __restrict__ ovmaxq)
{
  __shared__ float s_cv[KQ];     // 8.4 KB
  __shared__ int   s_ci[KQ];     // 8.4 KB
  __shared__ int   s_cnt;
  __shared__ float s_m[4];

  const int bm = blockIdx.x;
  const int q  = blockIdx.y;
  const int b  = bm >> 6;
  const int t  = threadIdx.x;
  const int wid = t >> 6, lane = t & 63;

  if (t == 0) s_cnt = 0;
  __syncthreads();

  const int   maskv = gt_mask[bm];
  const float4 g = *(const float4*)(gt_bboxes + (size_t)bm * 4);
  const int   label = gt_labels[bm];
  const int   kbeg = q * KQ, kend = kbeg + KQ;

  float* ovl_out = out + OUT_OVL + (size_t)bm * NK;
  const float4* pb  = (const float4*)(pred_bboxes + (size_t)b * NK * 4);
  const float2* pts = (const float2*)points;
  const float*  ps  = pred_scores + (size_t)b * NK * NC;
  const float*  pat = patan + (size_t)b * NK;

  const float w1 = g.z - g.x, h1 = g.w - g.y;
  const float at1 = atanf(w1 / (h1 + FEPS));
  const float area1 = w1 * h1;
  const float CV = (float)(4.0 / (M_PI * M_PI));
  const float ONE_EPS = (float)(1.0 + 1e-7);

  float lmax = 0.f;
  #pragma unroll
  for (int j = 0; j < 9; ++j) {
    const int k = kbeg + j * 256 + t;
    if (k < kend) {
      float ov = 0.f;
      if (maskv) {
        float2 p = pts[k];
        // diff.max(-1) < 1e-6 : four single-subtraction comparisons (exact f32)
        float dmax = fmaxf(fmaxf(g.x - p.x, g.y - p.y), fmaxf(p.x - g.z, p.y - g.w));
        if (dmax < 1e-6f) {
          float4 qb = pb[k];
          float w2 = qb.z - qb.x, h2 = qb.w - qb.y;
          float iw = fmaxf(fminf(g.z, qb.z) - fmaxf(g.x, qb.x), 0.f);
          float ih = fmaxf(fminf(g.w, qb.w) - fmaxf(g.y, qb.y), 0.f);
          float inter = iw * ih;
          float uni = area1 + w2 * h2 - inter + FEPS;
          float iou = inter / uni;
          float cw = fmaxf(g.z, qb.z) - fminf(g.x, qb.x);
          float ch = fmaxf(g.w, qb.w) - fminf(g.y, qb.y);
          float c2 = cw * cw + ch * ch + FEPS;
          float ex = qb.x + qb.z - g.x - g.z;
          float ey = qb.y + qb.w - g.y - g.w;
          float rho2 = (ex * ex + ey * ey) * 0.25f;
          float dat = pat[k] - at1;
          float v = CV * dat * dat;
          float alpha = v / (v - iou + ONE_EPS);
          float ciou = iou - (rho2 / c2 + alpha * v);
          ov = fmaxf(ciou, 0.f);
          float ts = ps[(size_t)k * NC + label];
          float o2 = ov * ov;
          float am = ts * (o2 * o2 * o2);   // ts**1 * ov**6
          if (am > 1e-9f) {                 // below cutoff can never be selected
            int p = atomicAdd(&s_cnt, 1);
            s_cv[p] = am; s_ci[p] = k;
          }
        }
      }
      ovl_out[k] = ov;
      lmax = fmaxf(lmax, ov);
    }
  }

  // partial row-max of overlaps
  float mv = lmax;
  #pragma unroll
  for (int d = 1; d < 64; d <<= 1) mv = fmaxf(mv, __shfl_xor(mv, d));
  if (lane == 0) s_m[wid] = mv;
  __syncthreads();
  if (t == 0)
    ovmaxq[bm * NQ + q] = fmaxf(fmaxf(s_m[0], s_m[1]), fmaxf(s_m[2], s_m[3]));

  if (wid != 0) return;           // extraction: wave 0 only
  const int n = s_cnt;

  // per-lane best over lane-strided slots; key = fbits(v)<<32 | ~ki
  unsigned long long bkey = 0; int bslot = -1;
  for (int e = lane; e < n; e += 64) {
    float v = s_cv[e];
    unsigned long long key =
        ((unsigned long long)__float_as_uint(v) << 32) |
        (unsigned long long)(0xFFFFFFFFu - (unsigned)s_ci[e]);
    if (key > bkey) { bkey = key; bslot = e; }
  }

  float* cv = candv + (size_t)(bm * NQ + q) * NT;
  int*   ci = candi + (size_t)(bm * NQ + q) * NT;
  int it = 0;
  for (; it < NT; ++it) {
    unsigned long long wkey = bkey;
    #pragma unroll
    for (int d = 1; d < 64; d <<= 1) {
      unsigned long long ok = __shfl_xor(wkey, d);
      if (ok > wkey) wkey = ok;
    }
    if (wkey == 0) break;         // all consumed (stored values are all >1e-9)
    if (lane == 0) {
      cv[it] = __uint_as_float((unsigned)(wkey >> 32));
      ci[it] = (int)(0xFFFFFFFFu - (unsigned)wkey);
    }
    if (bkey == wkey) {           // unique winner (ki unique)
      s_cv[bslot] = -1.f;
      bkey = 0; bslot = -1;
      for (int e = lane; e < n; e += 64) {
        float v = s_cv[e];
        if (v >= 0.f) {
          unsigned long long key =
              ((unsigned long long)__float_as_uint(v) << 32) |
              (unsigned long long)(0xFFFFFFFFu - (unsigned)s_ci[e]);
          if (key > bkey) { bkey = key; bslot = e; }
        }
      }
    }
  }
  if (lane == 0)
    for (int r = it; r < NT; ++r) { cv[r] = 0.f; ci[r] = -1; }
}

// ---------------------------------------------------------------------------
// kA2: one wave per (b,m): merge 4x15 quarter candidates -> global top-15
// (identical ordering to single-pass iterative argmax), fg0/flag atomics,
// ovmax merge.
// ---------------------------------------------------------------------------
__global__ __launch_bounds__(64) void kA2(
    const float* __restrict__ candv, const int* __restrict__ candi,
    const float* __restrict__ ovmaxq, float* __restrict__ ovmaxp,
    int* __restrict__ tki, float* __restrict__ tkv,
    int* __restrict__ fg0, int* __restrict__ flag)
{
  __shared__ int   s_wi[NT];
  __shared__ float s_wv[NT];
  const int bm = blockIdx.x;
  const int b  = bm >> 6;
  const int lane = threadIdx.x;

  if (lane == 0) {
    const float* om = ovmaxq + bm * NQ;
    ovmaxp[bm] = fmaxf(fmaxf(om[0], om[1]), fmaxf(om[2], om[3]));
  }

  unsigned long long bkey = 0;
  if (lane < NQ * NT) {
    int ki = candi[(size_t)bm * NQ * NT + lane];
    if (ki >= 0) {
      float v = candv[(size_t)bm * NQ * NT + lane];
      bkey = ((unsigned long long)__float_as_uint(v) << 32) |
             (unsigned long long)(0xFFFFFFFFu - (unsigned)ki);
    }
  }

  int nf = 0;
  for (int it = 0; it < NT; ++it) {
    unsigned long long wkey = bkey;
    #pragma unroll
    for (int d = 1; d < 64; d <<= 1) {
      unsigned long long ok = __shfl_xor(wkey, d);
      if (ok > wkey) wkey = ok;
    }
    if (wkey == 0) break;
    if (bkey == wkey) {           // unique winner stores round result
      s_wv[it] = __uint_as_float((unsigned)(wkey >> 32));
      s_wi[it] = (int)(0xFFFFFFFFu - (unsigned)wkey);
      bkey = 0;
    }
    nf = it + 1;
  }
  __syncthreads();                // one wave; cheap safety for LDS visibility

  if (lane < NT) {
    if (lane < nf) {
      int fi = s_wi[lane];
      tki[bm * NT + lane] = fi;
      tkv[bm * NT + lane] = s_wv[lane];
      int old = atomicAdd(&fg0[(size_t)b * NK + fi], 1);
      if (old >= 1) atomicOr(flag, 1);
    } else {
      tki[bm * NT + lane] = -1;
      tkv[bm * NT + lane] = 0.f;
    }
  }
}

// ---------------------------------------------------------------------------
// kMi: per (b,k), argmax over m of overlaps (first max wins)
// ---------------------------------------------------------------------------
__global__ __launch_bounds__(256) void kMi(const float* __restrict__ out,
                                           int* __restrict__ mi)
{
  const int b = blockIdx.y;
  const int k = blockIdx.x * 256 + threadIdx.x;
  if (k >= NK) return;
  const float* ovl = out + OUT_OVL + (size_t)b * NM * NK;
  float best = ovl[k]; int bi = 0;
  for (int m = 1; m < NM; ++m) {
    float v = ovl[(size_t)m * NK + k];
    if (v > best) { best = v; bi = m; }    // strict > keeps first max (jnp.argmax)
  }
  mi[(size_t)b * NK + k] = bi;
}

// ---------------------------------------------------------------------------
// kDE: per (b,k-tile) column block. Membership via LDS scatter of top-15
// lists; writes assign, fg, tgt_bboxes AND the fused tso slice.
// ---------------------------------------------------------------------------
constexpr int DH = 32;

__global__ __launch_bounds__(256) void kDE(
    const float* __restrict__ gt_bboxes, const int* __restrict__ gt_labels,
    const int* __restrict__ tki, const float* __restrict__ tkv,
    const float* __restrict__ ovmaxp, const int* __restrict__ mi,
    const int* __restrict__ flagp, float* __restrict__ out)
{
  __shared__ float  vals[DH][256];     // 32 KB
  __shared__ int    s_tki[NM * NT];
  __shared__ float  s_tkv[NM * NT];
  __shared__ float  s_rowmax[NM];
  __shared__ float  s_ovmax[NM];
  __shared__ int    s_label[NM];
  __shared__ float4 s_gtb[NM];
  __shared__ int    s_lab2[256];
  __shared__ float  s_tso2[256];

  const int b  = blockIdx.y;
  const int k0 = blockIdx.x * 256;
  const int t  = threadIdx.x;
  const int flag = *flagp;

  for (int e = t; e < NM * NT; e += 256) {
    s_tki[e] = tki[b * NM * NT + e];
    s_tkv[e] = tkv[b * NM * NT + e];
  }
  if (t < NM) {
    s_ovmax[t] = ovmaxp[b * NM + t];
    s_label[t] = gt_labels[b * NM + t];
    s_gtb[t] = *(const float4*)(gt_bboxes + (size_t)(b * NM + t) * 4);
  }
  __syncthreads();

  // post-filter row max of am_a over surviving top-15 entries
  if (t < NM) {
    float r = 0.f;
    for (int j = 0; j < NT; ++j) {
      int idx = s_tki[t * NT + j];
      if (idx >= 0 && (!flag || mi[(size_t)b * NK + idx] == t))
        r = fmaxf(r, s_tkv[t * NT + j]);
    }
    s_rowmax[t] = r;
  }

  const int k = k0 + t;
  const int mik = (k < NK) ? mi[(size_t)b * NK + k] : 0;
  int cnt = 0, tbi = -1;
  float factor = 0.f;

  for (int half = 0; half < 2; ++half) {
    __syncthreads();
    for (int e = t; e < DH * 256; e += 256) ((float*)vals)[e] = 0.f;
    __syncthreads();
    const int mbase = half * DH;
    for (int e = t; e < DH * NT; e += 256) {
      int mm = mbase + e / NT;
      int idx = s_tki[mm * NT + (e % NT)];
      if (idx >= k0 && idx < k0 + 256) vals[e / NT][idx - k0] = s_tkv[mm * NT + (e % NT)];
    }
    __syncthreads();
    if (k < NK) {
      for (int mo = 0; mo < DH; ++mo) {
        const int m = mbase + mo;
        float v = vals[mo][t];
        bool keep = (v > 1e-9f) && (!flag || mik == m);
        out[OUT_ASN + (size_t)(b * NM + m) * NK + k] = keep ? 1.f : 0.f;
        if (keep) {
          if (cnt == 0) tbi = m;
          cnt++;
          factor = fmaxf(factor, v / (s_rowmax[m] + 1e-9f) * s_ovmax[m]);
        }
      }
    }
  }

  if (k < NK) {
    const int tb = (tbi < 0) ? 0 : tbi;   // argmax of all-zero column -> 0
    out[OUT_FG + (size_t)b * NK + k] = (float)cnt;
    *(float4*)(out + OUT_TGT + (size_t)(b * NK + k) * 4) = s_gtb[tb];
    s_lab2[t] = s_label[tb];
    s_tso2[t] = (cnt > 0) ? factor : 0.f;
  }
  __syncthreads();

  // fused tso slice: 256 k x 80 classes, float4 stores
  float4* tso4 = (float4*)(out + OUT_TSO + (size_t)(b * NK + k0) * NC);
  for (int e = t; e < 256 * (NC / 4); e += 256) {
    const int kk = e / (NC / 4), c4 = e % (NC / 4);
    if (k0 + kk < NK) {
      const int lab = s_lab2[kk];
      const float tv = s_tso2[kk];
      float4 w = {0.f, 0.f, 0.f, 0.f};
      const int c = c4 * 4;
      if (lab >= c && lab < c + 4) ((float*)&w)[lab - c] = tv;
      tso4[(size_t)kk * (NC / 4) + c4] = w;
    }
  }
}

// ---------------------------------------------------------------------------
extern "C" void kernel_launch(void* const* d_in, const int* in_sizes, int n_in,
                              void* d_out, int out_size, void* d_ws, size_t ws_size,
                              hipStream_t stream)
{
  const float* points      = (const float*)d_in[0];
  const float* gt_bboxes   = (const float*)d_in[1];
  const int*   gt_labels   = (const int*)d_in[2];
  const float* pred_bboxes = (const float*)d_in[3];
  const float* pred_scores = (const float*)d_in[4];
  const int*   gt_mask     = (const int*)d_in[5];
  float* out = (float*)d_out;

  char* ws = (char*)d_ws;
  int*   tki    = (int*)ws;    ws += (size_t)NB * NM * NT * 4;
  float* tkv    = (float*)ws;  ws += (size_t)NB * NM * NT * 4;
  float* ovmaxp = (float*)ws;  ws += (size_t)NB * NM * 4;
  int*   mi     = (int*)ws;    ws += (size_t)NB * NK * 4;
  int*   fg0    = (int*)ws;    ws += (size_t)NB * NK * 4;
  int*   flag   = (int*)ws;    ws += 256;                      // 4B used
  float* patan  = (float*)ws;  ws += (size_t)NB * NK * 4;
  float* candv  = (float*)ws;  ws += (size_t)NB * NM * NQ * NT * 4;
  int*   candi  = (int*)ws;    ws += (size_t)NB * NM * NQ * NT * 4;
  float* ovmaxq = (float*)ws;  ws += (size_t)NB * NM * NQ * 4;

  // fg0 + flag must be zero at the start of every call
  hipMemsetAsync(fg0, 0, (size_t)NB * NK * 4 + 256, stream);

  kP<<<(NB * NK + 255) / 256, 256, 0, stream>>>(pred_bboxes, patan);

  dim3 gA1(NB * NM, NQ);
  kA1<<<gA1, 256, 0, stream>>>(points, gt_bboxes, gt_labels, pred_bboxes,
                               pred_scores, gt_mask, patan, out, candv, candi,
                               ovmaxq);

  kA2<<<NB * NM, 64, 0, stream>>>(candv, candi, ovmaxq, ovmaxp, tki, tkv,
                                  fg0, flag);

  dim3 g2((NK + 255) / 256, NB);
  kMi<<<g2, 256, 0, stream>>>(out, mi);
  kDE<<<g2, 256, 0, stream>>>(gt_bboxes, gt_labels, tki, tkv, ovmaxp, mi, flag,
                              out);
}

// Round 4
// 117.734 us; speedup vs baseline: 2.1481x; 1.3034x over previous
//
#include <hip/hip_runtime.h>
#include <math.h>

// Problem constants (match reference)
constexpr int NB = 32, NM = 64, NK = 8400, NC = 80, NT = 15;
constexpr int NQ = 4, KQ = 2100;       // k split into 4 quarters of 2100
constexpr float FEPS = 1e-7f;

// Output layout: [tso | tgt_bboxes | assign | overlaps | fg], all float32
constexpr size_t OUT_TSO = 0;
constexpr size_t OUT_TGT = (size_t)NB * NK * NC;            // 21504000
constexpr size_t OUT_ASN = OUT_TGT + (size_t)NB * NK * 4;   // 22579200
constexpr size_t OUT_OVL = OUT_ASN + (size_t)NB * NM * NK;  // 39782400
constexpr size_t OUT_FG  = OUT_OVL + (size_t)NB * NM * NK;  // 56985600

// ---------------------------------------------------------------------------
// kP: patan[b,k] = atanf(w2/(h2+eps)) — hoists atanf out of the (m) loop
// ---------------------------------------------------------------------------
__global__ __launch_bounds__(256) void kP(const float* __restrict__ pred_bboxes,
                                          float* __restrict__ patan)
{
  const int i = blockIdx.x * 256 + threadIdx.x;
  if (i >= NB * NK) return;
  float4 q = ((const float4*)pred_bboxes)[i];
  patan[i] = atanf((q.z - q.x) / ((q.w - q.y) + FEPS));
}

// ---------------------------------------------------------------------------
// kA: one block per (b,m,quarter). Two passes:
//   pass 1: cheap point-in-box test -> LDS list of positive k (~3%)
//   pass 2: CIoU only on positives; scattered overlaps writes (zeros come
//           from the d_out memset); mi via u64 atomicMax key; am candidates
//           collected and reduced to per-quarter top-15 (value desc, idx asc).
// ---------------------------------------------------------------------------
__global__ __launch_bounds__(256) void kA(
    const float* __restrict__ points, const float* __restrict__ gt_bboxes,
    const int* __restrict__ gt_labels, const float* __restrict__ pred_bboxes,
    const float* __restrict__ pred_scores, const int* __restrict__ gt_mask,
    const float* __restrict__ patan, float* __restrict__ out,
    float* __restrict__ candv, int* __restrict__ candi,
    float* __restrict__ ovmaxq, unsigned long long* __restrict__ mikey)
{
  __shared__ int   s_pos[KQ];    // 8.4 KB positive-k list
  __shared__ float s_cv[KQ];     // 8.4 KB candidate am
  __shared__ int   s_ci[KQ];     // 8.4 KB candidate k
  __shared__ int   s_np, s_cnt;
  __shared__ float s_m[4];

  const int bm = blockIdx.x;
  const int q  = blockIdx.y;
  const int b  = bm >> 6;
  const int m  = bm & 63;
  const int t  = threadIdx.x;
  const int wid = t >> 6, lane = t & 63;

  float* cv = candv + (size_t)(bm * NQ + q) * NT;
  int*   ci = candi + (size_t)(bm * NQ + q) * NT;

  const int maskv = gt_mask[bm];
  if (!maskv) {
    if (t == 0) ovmaxq[bm * NQ + q] = 0.f;
    if (t < NT) { cv[t] = 0.f; ci[t] = -1; }
    return;
  }
  if (t == 0) { s_np = 0; s_cnt = 0; }
  __syncthreads();

  const float4 g = *(const float4*)(gt_bboxes + (size_t)bm * 4);
  const int   label = gt_labels[bm];
  const int   kbeg = q * KQ, kend = kbeg + KQ;
  const float2* pts = (const float2*)points;

  // pass 1: point-in-box (diff.max(-1) < 1e-6, exact f32 single-subtractions)
  #pragma unroll
  for (int j = 0; j < 9; ++j) {
    const int k = kbeg + j * 256 + t;
    if (k < kend) {
      float2 p = pts[k];
      float dmax = fmaxf(fmaxf(g.x - p.x, g.y - p.y), fmaxf(p.x - g.z, p.y - g.w));
      if (dmax < 1e-6f) { int e = atomicAdd(&s_np, 1); s_pos[e] = k; }
    }
  }
  __syncthreads();
  const int np = s_np;

  const float4* pb  = (const float4*)(pred_bboxes + (size_t)b * NK * 4);
  const float*  ps  = pred_scores + (size_t)b * NK * NC;
  const float*  pat = patan + (size_t)b * NK;
  float* ovl_out = out + OUT_OVL + (size_t)bm * NK;
  unsigned long long* mk = mikey + (size_t)b * NK;

  const float w1 = g.z - g.x, h1 = g.w - g.y;
  const float at1 = atanf(w1 / (h1 + FEPS));
  const float area1 = w1 * h1;
  const float CV = (float)(4.0 / (M_PI * M_PI));
  const float ONE_EPS = (float)(1.0 + 1e-7);

  float lmax = 0.f;
  for (int e = t; e < np; e += 256) {
    const int k = s_pos[e];
    float4 qb = pb[k];
    float w2 = qb.z - qb.x, h2 = qb.w - qb.y;
    float iw = fmaxf(fminf(g.z, qb.z) - fmaxf(g.x, qb.x), 0.f);
    float ih = fmaxf(fminf(g.w, qb.w) - fmaxf(g.y, qb.y), 0.f);
    float inter = iw * ih;
    float uni = area1 + w2 * h2 - inter + FEPS;
    float iou = inter / uni;
    float cw = fmaxf(g.z, qb.z) - fminf(g.x, qb.x);
    float ch = fmaxf(g.w, qb.w) - fminf(g.y, qb.y);
    float c2 = cw * cw + ch * ch + FEPS;
    float ex = qb.x + qb.z - g.x - g.z;
    float ey = qb.y + qb.w - g.y - g.w;
    float rho2 = (ex * ex + ey * ey) * 0.25f;
    float dat = pat[k] - at1;
    float v = CV * dat * dat;
    float alpha = v / (v - iou + ONE_EPS);
    float ciou = iou - (rho2 / c2 + alpha * v);
    float ov = fmaxf(ciou, 0.f);
    if (ov > 0.f) {
      ovl_out[k] = ov;                                  // zeros come from memset
      unsigned long long key =
          ((unsigned long long)__float_as_uint(ov) << 32) |
          (unsigned long long)(NM - 1 - m);             // value desc, first-m tie
      atomicMax(&mk[k], key);
      lmax = fmaxf(lmax, ov);
      float ts = ps[(size_t)k * NC + label];
      float o2 = ov * ov;
      float am = ts * (o2 * o2 * o2);                   // ts**1 * ov**6
      if (am > 1e-9f) {                                 // below cutoff never selected
        int p2 = atomicAdd(&s_cnt, 1);
        s_cv[p2] = am; s_ci[p2] = k;
      }
    }
  }

  // partial row-max of overlaps
  float mv = lmax;
  #pragma unroll
  for (int d = 1; d < 64; d <<= 1) mv = fmaxf(mv, __shfl_xor(mv, d));
  if (lane == 0) s_m[wid] = mv;
  __syncthreads();   // also finalizes s_cnt/s_cv/s_ci
  if (t == 0)
    ovmaxq[bm * NQ + q] = fmaxf(fmaxf(s_m[0], s_m[1]), fmaxf(s_m[2], s_m[3]));

  if (wid != 0) return;           // extraction: wave 0 only
  const int n = s_cnt;

  // per-lane best over lane-strided slots; key = fbits(v)<<32 | ~ki
  unsigned long long bkey = 0; int bslot = -1;
  for (int e = lane; e < n; e += 64) {
    float v = s_cv[e];
    unsigned long long key =
        ((unsigned long long)__float_as_uint(v) << 32) |
        (unsigned long long)(0xFFFFFFFFu - (unsigned)s_ci[e]);
    if (key > bkey) { bkey = key; bslot = e; }
  }

  int it = 0;
  for (; it < NT; ++it) {
    unsigned long long wkey = bkey;
    #pragma unroll
    for (int d = 1; d < 64; d <<= 1) {
      unsigned long long ok = __shfl_xor(wkey, d);
      if (ok > wkey) wkey = ok;
    }
    if (wkey == 0) break;         // all consumed
    if (lane == 0) {
      cv[it] = __uint_as_float((unsigned)(wkey >> 32));
      ci[it] = (int)(0xFFFFFFFFu - (unsigned)wkey);
    }
    if (bkey == wkey) {           // unique winner (ki unique)
      s_cv[bslot] = -1.f;
      bkey = 0; bslot = -1;
      for (int e = lane; e < n; e += 64) {
        float v = s_cv[e];
        if (v >= 0.f) {
          unsigned long long key =
              ((unsigned long long)__float_as_uint(v) << 32) |
              (unsigned long long)(0xFFFFFFFFu - (unsigned)s_ci[e]);
          if (key > bkey) { bkey = key; bslot = e; }
        }
      }
    }
  }
  if (lane == 0)
    for (int r = it; r < NT; ++r) { cv[r] = 0.f; ci[r] = -1; }
}

// ---------------------------------------------------------------------------
// kA2: one wave per (b,m): merge 4x15 quarter candidates -> global top-15
// (identical ordering to single-pass iterative argmax), fg0/flag atomics,
// ovmax merge.
// ---------------------------------------------------------------------------
__global__ __launch_bounds__(64) void kA2(
    const float* __restrict__ candv, const int* __restrict__ candi,
    const float* __restrict__ ovmaxq, float* __restrict__ ovmaxp,
    int* __restrict__ tki, float* __restrict__ tkv,
    int* __restrict__ fg0, int* __restrict__ flag)
{
  __shared__ int   s_wi[NT];
  __shared__ float s_wv[NT];
  const int bm = blockIdx.x;
  const int b  = bm >> 6;
  const int lane = threadIdx.x;

  if (lane == 0) {
    const float* om = ovmaxq + bm * NQ;
    ovmaxp[bm] = fmaxf(fmaxf(om[0], om[1]), fmaxf(om[2], om[3]));
  }

  unsigned long long bkey = 0;
  if (lane < NQ * NT) {
    int ki = candi[(size_t)bm * NQ * NT + lane];
    if (ki >= 0) {
      float v = candv[(size_t)bm * NQ * NT + lane];
      bkey = ((unsigned long long)__float_as_uint(v) << 32) |
             (unsigned long long)(0xFFFFFFFFu - (unsigned)ki);
    }
  }

  int nf = 0;
  for (int it = 0; it < NT; ++it) {
    unsigned long long wkey = bkey;
    #pragma unroll
    for (int d = 1; d < 64; d <<= 1) {
      unsigned long long ok = __shfl_xor(wkey, d);
      if (ok > wkey) wkey = ok;
    }
    if (wkey == 0) break;
    if (bkey == wkey) {           // unique winner stores round result
      s_wv[it] = __uint_as_float((unsigned)(wkey >> 32));
      s_wi[it] = (int)(0xFFFFFFFFu - (unsigned)wkey);
      bkey = 0;
    }
    nf = it + 1;
  }
  __syncthreads();

  if (lane < NT) {
    if (lane < nf) {
      int fi = s_wi[lane];
      tki[bm * NT + lane] = fi;
      tkv[bm * NT + lane] = s_wv[lane];
      int old = atomicAdd(&fg0[(size_t)b * NK + fi], 1);
      if (old >= 1) atomicOr(flag, 1);
    } else {
      tki[bm * NT + lane] = -1;
      tkv[bm * NT + lane] = 0.f;
    }
  }
}

// ---------------------------------------------------------------------------
// kF: per (b, 256-k tile). Post-filter fg is 0/1 => unique entry per k.
// Scatter kept entries into LDS slot map; write fg (dense), tgt (dense f4),
// the single tso element per hit, and the assign ones. Zeros from memset.
// ---------------------------------------------------------------------------
__global__ __launch_bounds__(256) void kF(
    const float* __restrict__ gt_bboxes, const int* __restrict__ gt_labels,
    const int* __restrict__ tki, const float* __restrict__ tkv,
    const float* __restrict__ ovmaxp, const unsigned long long* __restrict__ mikey,
    const int* __restrict__ flagp, float* __restrict__ out)
{
  __shared__ int    s_tki[NM * NT];
  __shared__ float  s_tkv[NM * NT];
  __shared__ unsigned char s_keep[NM * NT];
  __shared__ float  s_rowmax[NM];
  __shared__ float  s_ovmax[NM];
  __shared__ int    s_label[NM];
  __shared__ float4 s_gtb[NM];
  __shared__ int    s_mk[256];
  __shared__ float  s_sv[256];

  const int b  = blockIdx.y;
  const int k0 = blockIdx.x * 256;
  const int t  = threadIdx.x;
  const int flag = *flagp;

  for (int e = t; e < NM * NT; e += 256) {
    s_tki[e] = tki[b * NM * NT + e];
    s_tkv[e] = tkv[b * NM * NT + e];
  }
  if (t < NM) {
    s_ovmax[t] = ovmaxp[b * NM + t];
    s_label[t] = gt_labels[b * NM + t];
    s_gtb[t] = *(const float4*)(gt_bboxes + (size_t)(b * NM + t) * 4);
  }
  s_mk[t] = -1;
  s_sv[t] = 0.f;
  __syncthreads();

  // keep flags + post-filter row max of am over surviving entries
  if (t < NM) {
    float r = 0.f;
    for (int j = 0; j < NT; ++j) {
      const int e = t * NT + j;
      const int idx = s_tki[e];
      bool kp = (idx >= 0);
      if (kp && flag) {
        unsigned long long key = mikey[(size_t)b * NK + idx];
        int mi = NM - 1 - (int)(key & 0xFFFFFFFFull);   // key>0 for valid entries
        kp = (mi == t);
      }
      s_keep[e] = kp;
      if (kp) r = fmaxf(r, s_tkv[e]);
    }
    s_rowmax[t] = r;
  }
  __syncthreads();

  // scatter kept entries whose idx lands in this tile (unique per k)
  for (int e = t; e < NM * NT; e += 256) {
    if (!s_keep[e]) continue;
    const int idx = s_tki[e];
    if (idx < k0 || idx >= k0 + 256) continue;
    const int m = e / NT;
    const float sv = s_tkv[e] / (s_rowmax[m] + 1e-9f) * s_ovmax[m];
    s_mk[idx - k0] = m;
    s_sv[idx - k0] = sv;
    out[OUT_ASN + (size_t)(b * NM + m) * NK + idx] = 1.f;
  }
  __syncthreads();

  const int k = k0 + t;
  if (k < NK) {
    const int mk2 = s_mk[t];
    const int tb = (mk2 >= 0) ? mk2 : 0;   // argmax of all-zero column -> 0
    out[OUT_FG + (size_t)b * NK + k] = (mk2 >= 0) ? 1.f : 0.f;
    *(float4*)(out + OUT_TGT + (size_t)(b * NK + k) * 4) = s_gtb[tb];
    if (mk2 >= 0)
      out[OUT_TSO + (size_t)(b * NK + k) * NC + s_label[mk2]] = s_sv[t];
  }
}

// ---------------------------------------------------------------------------
extern "C" void kernel_launch(void* const* d_in, const int* in_sizes, int n_in,
                              void* d_out, int out_size, void* d_ws, size_t ws_size,
                              hipStream_t stream)
{
  const float* points      = (const float*)d_in[0];
  const float* gt_bboxes   = (const float*)d_in[1];
  const int*   gt_labels   = (const int*)d_in[2];
  const float* pred_bboxes = (const float*)d_in[3];
  const float* pred_scores = (const float*)d_in[4];
  const int*   gt_mask     = (const int*)d_in[5];
  float* out = (float*)d_out;

  char* ws = (char*)d_ws;
  // zero-initialized block first (one small memset): mikey | fg0 | flag
  unsigned long long* mikey = (unsigned long long*)ws; ws += (size_t)NB * NK * 8;
  int*   fg0    = (int*)ws;    ws += (size_t)NB * NK * 4;
  int*   flag   = (int*)ws;    ws += 256;
  const size_t zbytes = (size_t)NB * NK * 12 + 256;
  // not memset:
  int*   tki    = (int*)ws;    ws += (size_t)NB * NM * NT * 4;
  float* tkv    = (float*)ws;  ws += (size_t)NB * NM * NT * 4;
  float* ovmaxp = (float*)ws;  ws += (size_t)NB * NM * 4;
  float* patan  = (float*)ws;  ws += (size_t)NB * NK * 4;
  float* candv  = (float*)ws;  ws += (size_t)NB * NM * NQ * NT * 4;
  int*   candi  = (int*)ws;    ws += (size_t)NB * NM * NQ * NT * 4;
  float* ovmaxq = (float*)ws;  ws += (size_t)NB * NM * NQ * 4;

  // all zeros of tso/assign/overlaps (and tgt/fg, overwritten densely later)
  hipMemsetAsync(d_out, 0, (size_t)out_size * 4, stream);
  hipMemsetAsync(mikey, 0, zbytes, stream);

  kP<<<(NB * NK + 255) / 256, 256, 0, stream>>>(pred_bboxes, patan);

  dim3 gA(NB * NM, NQ);
  kA<<<gA, 256, 0, stream>>>(points, gt_bboxes, gt_labels, pred_bboxes,
                             pred_scores, gt_mask, patan, out, candv, candi,
                             ovmaxq, mikey);

  kA2<<<NB * NM, 64, 0, stream>>>(candv, candi, ovmaxq, ovmaxp, tki, tkv,
                                  fg0, flag);

  dim3 g2((NK + 255) / 256, NB);
  kF<<<g2, 256, 0, stream>>>(gt_bboxes, gt_labels, tki, tkv, ovmaxp, mikey,
                             flag, out);
}